// Round 6
// baseline (786.709 us; speedup 1.0000x reference)
//
#include <hip/hip_runtime.h>
#include <hip/hip_bf16.h>

typedef int  int4v  __attribute__((ext_vector_type(4)));
typedef int  int16v __attribute__((ext_vector_type(16)));

#define M_DIM 4096
#define N_DIM 4096
#define K_DIM 4096
#define NG 32        // groups
#define GS 128       // group size

// ---------------- fused prepass ----------------
// blocks [0, 4096): per-row absmax-quantize x -> xq i8 [M][K], sx[m]=absmax/127
// blocks [4096, 8192): wq[n][k] = q[k][n] - zp[g][n]  (exact in i8, transposed
//   via LDS tile so global writes are 128B-contiguous)
__global__ void prep_kernel(const float* __restrict__ x,
                            signed char* __restrict__ xq,
                            float* __restrict__ sx,
                            const int* __restrict__ qw,
                            const int* __restrict__ zps,
                            signed char* __restrict__ wq) {
    const int tid = threadIdx.x;
    if (blockIdx.x < 4096) {
        __shared__ float red[4];
        __shared__ float inv_s;
        const int m = blockIdx.x;
        const float4* xr = reinterpret_cast<const float4*>(x + (long)m * K_DIM);
        float4 v[4];
        float amax = 0.f;
#pragma unroll
        for (int j = 0; j < 4; ++j) {
            v[j] = xr[tid * 4 + j];
            amax = fmaxf(amax, fmaxf(fmaxf(fabsf(v[j].x), fabsf(v[j].y)),
                                     fmaxf(fabsf(v[j].z), fabsf(v[j].w))));
        }
#pragma unroll
        for (int off = 32; off >= 1; off >>= 1)
            amax = fmaxf(amax, __shfl_xor(amax, off));
        if ((tid & 63) == 0) red[tid >> 6] = amax;
        __syncthreads();
        if (tid == 0) {
            float a = fmaxf(fmaxf(red[0], red[1]), fmaxf(red[2], red[3]));
            sx[m] = a * (1.f / 127.f);
            inv_s = (a > 0.f) ? 127.f / a : 0.f;
        }
        __syncthreads();
        const float inv = inv_s;
        unsigned p[4];
#pragma unroll
        for (int j = 0; j < 4; ++j) {
            int a0 = __float2int_rn(v[j].x * inv);
            int a1 = __float2int_rn(v[j].y * inv);
            int a2 = __float2int_rn(v[j].z * inv);
            int a3 = __float2int_rn(v[j].w * inv);
            p[j] = (a0 & 255) | ((a1 & 255) << 8) | ((a2 & 255) << 16) | ((a3 & 255) << 24);
        }
        *reinterpret_cast<uint4*>(xq + (long)m * K_DIM + tid * 16) =
            make_uint4(p[0], p[1], p[2], p[3]);
        return;
    }
    // ---- wq half: tile = 128 k-rows x 32 n-cols, LDS transpose ----
    __shared__ signed char lt[128 * 32];
    const int bx = blockIdx.x - 4096;
    const int n0 = (bx & 127) * 32;
    const int k0 = (bx >> 7) * 128;     // tile spans exactly one scale group
    const int g  = bx >> 7;
    const int kl = tid >> 1;            // 0..127
    const int h  = tid & 1;
    int4 qv[4], zv[4];
#pragma unroll
    for (int c = 0; c < 4; ++c) {
        qv[c] = *reinterpret_cast<const int4*>(&qw[(long)(k0 + kl) * N_DIM + n0 + h * 16 + c * 4]);
        zv[c] = *reinterpret_cast<const int4*>(&zps[(long)g * N_DIM + n0 + h * 16 + c * 4]);
    }
    {
        const int swz = ((kl >> 3) & 7) << 2;
        int* ltw = reinterpret_cast<int*>(lt);
#pragma unroll
        for (int c = 0; c < 4; ++c) {
            unsigned d = (unsigned)((qv[c].x - zv[c].x) & 255)
                       | ((unsigned)((qv[c].y - zv[c].y) & 255) << 8)
                       | ((unsigned)((qv[c].z - zv[c].z) & 255) << 16)
                       | ((unsigned)((qv[c].w - zv[c].w) & 255) << 24);
            ltw[(kl * 32 + ((h * 16 + c * 4) ^ swz)) >> 2] = d;
        }
    }
    __syncthreads();
    const int nl = tid >> 3;            // 0..31
    const int kq = tid & 7;             // 0..7
    unsigned acc[4] = {0u, 0u, 0u, 0u};
#pragma unroll
    for (int j = 0; j < 16; ++j) {
        const int kr = kq * 16 + j;
        unsigned by = (unsigned char)lt[kr * 32 + (nl ^ (((kr >> 3) & 7) << 2))];
        acc[j >> 2] |= by << (8 * (j & 3));
    }
    *reinterpret_cast<uint4*>(wq + (long)(n0 + nl) * K_DIM + k0 + kq * 16) =
        make_uint4(acc[0], acc[1], acc[2], acc[3]);
}

// ---------------- main GEMM (i8): C = sx[m] * sum_g s[g][n]*(xq . wq) + bias
// 256x256 tile, 512 thr (8 waves 2x4), wave tile 128x64.
// m201-style deep pipeline: K_STEP=64, 4-buffer LDS ring (128 KiB), staging
// issued TWO steps ahead; counted `s_waitcnt vmcnt(4)` once per step (never
// 0 in steady state -- the 4 newest outstanding are step-(t+2)'s loads;
// anything older, incl. step-(t+1)'s, is forced complete). vmcnt(0) only in
// the 2-step tail. Raw s_barrier (no vmcnt drain) with compiler-only memory
// fences; NO sched_barrier(0) (round-5 spill trigger). 2 phases/step by
// mt-pair: {deferred-rescale | ds_read frags | stage-issue -> barrier ->
// setprio(1) 8 MFMA setprio(0) -> barrier}: pre-barrier work overlaps other
// waves' MFMA. Rescale per 64-k step (scales constant within the 128-k
// group -> identical math, halves c liveness: one transient c-pair).
// LDS 64B-row XOR swizzle: slot' = u ^ ((row>>1)&3); write side lane-linear
// 1024B/wave, read side uniform 8 dwords/bank -> conflict-free both ways.
// A/B frags use the IDENTICAL (ks,half)->16B-unit bijection, so correctness
// is independent of MFMA's internal k-order.
#define BM 256
#define BN 256
#define KS 64
#define NSTEP (K_DIM / KS)   // 64

__device__ __forceinline__ void async_ld16(const signed char* g, const signed char* l) {
    __builtin_amdgcn_global_load_lds(
        (const __attribute__((address_space(1))) void*)g,
        (__attribute__((address_space(3))) void*)l, 16, 0, 0);
}

__device__ __forceinline__ int16v mf(const int4v a, const int4v b, const int16v c) {
    return __builtin_amdgcn_mfma_i32_32x32x32_i8(a, b, c, 0, 0, 0);
}

__device__ __forceinline__ int4v ld_frag(const signed char* buf, int row, int u) {
    const int phys = u ^ ((row >> 1) & 3);
    return *reinterpret_cast<const int4v*>(&buf[row * KS + phys * 16]);
}

__device__ __forceinline__ void wg_barrier() {
    asm volatile("" ::: "memory");
    __builtin_amdgcn_s_barrier();
    asm volatile("" ::: "memory");
}

template <int P>
__device__ __forceinline__ void read_af_pair(const signed char* Ab, int wm, int l32,
                                             int half, int4v af[2][2]) {
#pragma unroll
    for (int mtl = 0; mtl < 2; ++mtl) {
        const int m = wm + (2 * P + mtl) * 32 + l32;
#pragma unroll
        for (int ks = 0; ks < 2; ++ks)
            af[mtl][ks] = ld_frag(Ab, m, 2 * ks + half);
    }
}

__device__ __forceinline__ void mfma8(const int4v af[2][2], const int4v bf[2][2],
                                      int16v c[2][2]) {
    int16v z;
#pragma unroll
    for (int r = 0; r < 16; ++r) z[r] = 0;
#pragma unroll
    for (int mtl = 0; mtl < 2; ++mtl)
#pragma unroll
        for (int nt = 0; nt < 2; ++nt) {
            int16v t0 = mf(af[mtl][0], bf[nt][0], z);
            c[mtl][nt] = mf(af[mtl][1], bf[nt][1], t0);
        }
}

template <int P>
__device__ __forceinline__ void rescale_pair(const int16v c[2][2], float s0, float s1,
                                             float facc[4][2][16]) {
#pragma unroll
    for (int mtl = 0; mtl < 2; ++mtl)
#pragma unroll
        for (int r = 0; r < 16; ++r) {
            facc[2 * P + mtl][0][r] += s0 * (float)c[mtl][0][r];
            facc[2 * P + mtl][1][r] += s1 * (float)c[mtl][1][r];
        }
}

__global__ __launch_bounds__(512, 2) void gemm_kernel(
    const signed char* __restrict__ A,   // xq [M][K]
    const signed char* __restrict__ Bq,  // wq [N][K]
    const float* __restrict__ scales,    // [NG][N]
    const float* __restrict__ sx,        // [M]
    const float* __restrict__ bias,      // [N]
    float* __restrict__ C) {
    __shared__ signed char As[4][BM * KS];  // 4 x 16 KB
    __shared__ signed char Bs[4][BN * KS];  // 4 x 16 KB  (total 128 KiB)
    const int tid  = threadIdx.x;
    const int wave = tid >> 6;
    const int lane = tid & 63;
    const int half = lane >> 5;
    const int l32  = lane & 31;
    const int wm = (wave >> 2) * 128;
    const int wn = (wave & 3) * 64;

    // bijective XCD swizzle: 256 blocks, 32 consecutive per XCD
    const int bid = (int)blockIdx.x;
    const int swz = (bid & 7) * 32 + (bid >> 3);
    const int m0 = (swz >> 4) * BM;
    const int n0 = (swz & 15) * BN;

    // DMA staging: thread -> row = tid/4 (+128 on 2nd pass), 16B slot tid&3;
    // global unit = (tid&3) ^ ((row>>1)&3)  [involution matches ld_frag]
    const int srow  = tid >> 2;
    const int sunit = (tid & 3) ^ ((tid >> 3) & 3);
    const signed char* agp = A  + (long)(m0 + srow) * K_DIM + sunit * 16;
    const signed char* bgp = Bq + (long)(n0 + srow) * K_DIM + sunit * 16;
    const float* sp = scales + n0 + wn + l32;

    float facc[4][2][16];
#pragma unroll
    for (int mt = 0; mt < 4; ++mt)
#pragma unroll
        for (int nt = 0; nt < 2; ++nt)
#pragma unroll
            for (int r = 0; r < 16; ++r) facc[mt][nt][r] = 0.f;

    // prologue: stage steps 0 and 1 (8 loads), wait step-0 (allow step-1's 4)
    async_ld16(agp,                          As[0] + wave * 1024);
    async_ld16(agp + (long)128 * K_DIM,      As[0] + 8192 + wave * 1024);
    async_ld16(bgp,                          Bs[0] + wave * 1024);
    async_ld16(bgp + (long)128 * K_DIM,      Bs[0] + 8192 + wave * 1024);
    async_ld16(agp + KS,                     As[1] + wave * 1024);
    async_ld16(agp + (long)128 * K_DIM + KS, As[1] + 8192 + wave * 1024);
    async_ld16(bgp + KS,                     Bs[1] + wave * 1024);
    async_ld16(bgp + (long)128 * K_DIM + KS, Bs[1] + 8192 + wave * 1024);
    asm volatile("s_waitcnt vmcnt(4)" ::: "memory");
    wg_barrier();

    int4v af[2][2], bf[2][2];
    int16v c[2][2];
    float s0c = 0.f, s1c = 0.f;

    for (int t = 0; t < NSTEP; ++t) {
        const signed char* Ab = As[t & 3];
        const signed char* Bb = Bs[t & 3];
        signed char* An = As[(t + 2) & 3];
        signed char* Bn = Bs[(t + 2) & 3];
        const bool pf = (t + 2 < NSTEP);
        const long ko2 = (long)(t + 2) * KS;

        // ===== phase 0: pair0 (mt 0,1) =====
        if (t > 0) rescale_pair<1>(c, s0c, s1c, facc);   // pair1 of step t-1 (same/prev group scales)
        if ((t & 1) == 0) {                              // new group: reload scales
            s0c = sp[(long)(t >> 1) * N_DIM];
            s1c = sp[(long)(t >> 1) * N_DIM + 32];
        }
        read_af_pair<0>(Ab, wm, l32, half, af);
#pragma unroll
        for (int nt = 0; nt < 2; ++nt) {
            const int n = wn + nt * 32 + l32;
#pragma unroll
            for (int ks = 0; ks < 2; ++ks)
                bf[nt][ks] = ld_frag(Bb, n, 2 * ks + half);
        }
        if (pf) {
            async_ld16(agp + ko2,                     An + wave * 1024);
            async_ld16(agp + (long)128 * K_DIM + ko2, An + 8192 + wave * 1024);
        }
        wg_barrier();
        __builtin_amdgcn_s_setprio(1);
        mfma8(af, bf, c);
        __builtin_amdgcn_s_setprio(0);
        wg_barrier();

        // ===== phase 1: pair1 (mt 2,3) =====
        rescale_pair<0>(c, s0c, s1c, facc);              // pair0 of this step
        read_af_pair<1>(Ab, wm, l32, half, af);
        if (pf) {
            async_ld16(bgp + ko2,                     Bn + wave * 1024);
            async_ld16(bgp + (long)128 * K_DIM + ko2, Bn + 8192 + wave * 1024);
            // newest 4 outstanding = step-(t+2)'s loads; forces step-(t+1) complete
            asm volatile("s_waitcnt vmcnt(4)" ::: "memory");
        } else {
            asm volatile("s_waitcnt vmcnt(0)" ::: "memory");
        }
        wg_barrier();
        __builtin_amdgcn_s_setprio(1);
        mfma8(af, bf, c);
        __builtin_amdgcn_s_setprio(0);
        wg_barrier();
    }
    rescale_pair<1>(c, s0c, s1c, facc);                  // pair1 of final step

    // epilogue: 32x32 C/D layout col=lane&31, row=(reg&3)+8*(reg>>2)+4*half
    float bv[2];
    bv[0] = bias[n0 + wn + l32];
    bv[1] = bias[n0 + wn + 32 + l32];
    const int rowh = half * 4;
#pragma unroll
    for (int mt = 0; mt < 4; ++mt) {
#pragma unroll
        for (int r = 0; r < 16; ++r) {
            const int row = (r & 3) + 8 * (r >> 2) + rowh;
            const int gm  = m0 + wm + mt * 32 + row;
            const float sxm = sx[gm];
            float* crow = C + (long)gm * N_DIM + n0 + wn;
            crow[l32]      = facc[mt][0][r] * sxm + bv[0];
            crow[32 + l32] = facc[mt][1][r] * sxm + bv[1];
        }
    }
}

extern "C" void kernel_launch(void* const* d_in, const int* in_sizes, int n_in,
                              void* d_out, int out_size, void* d_ws, size_t ws_size,
                              hipStream_t stream) {
    const float* x      = (const float*)d_in[0];
    const int*   qw     = (const int*)d_in[1];
    const float* scales = (const float*)d_in[2];
    const int*   zps    = (const int*)d_in[3];
    // d_in[4] = g_idx: standard non-permuted (k/128) — folded in.
    const float* bias   = (const float*)d_in[5];
    float* out = (float*)d_out;

    signed char* xq = (signed char*)d_ws;                                   // 16 MB
    signed char* wq = (signed char*)d_ws + (size_t)M_DIM * K_DIM;           // 16 MB
    float*       sx = (float*)((signed char*)d_ws + 2 * (size_t)M_DIM * K_DIM);  // 16 KB

    prep_kernel<<<8192, 256, 0, stream>>>(x, xq, sx, qw, zps, wq);
    gemm_kernel<<<N_DIM / BN * (M_DIM / BM), 512, 0, stream>>>(
        xq, wq, scales, sx, bias, out);
}

// Round 7
// 295.204 us; speedup vs baseline: 2.6650x; 2.6650x over previous
//
#include <hip/hip_runtime.h>
#include <hip/hip_bf16.h>

typedef int  int4v  __attribute__((ext_vector_type(4)));
typedef int  int16v __attribute__((ext_vector_type(16)));

#define M_DIM 4096
#define N_DIM 4096
#define K_DIM 4096
#define NG 32        // groups
#define GS 128       // group size

// ---------------- fused prepass ----------------
// blocks [0, 4096): per-row absmax-quantize x -> xq i8 [M][K], sx[m]=absmax/127
// blocks [4096, 8192): wq[n][k] = q[k][n] - zp[g][n]  (exact in i8, transposed
//   via LDS tile so global writes are 128B-contiguous)
__global__ void prep_kernel(const float* __restrict__ x,
                            signed char* __restrict__ xq,
                            float* __restrict__ sx,
                            const int* __restrict__ qw,
                            const int* __restrict__ zps,
                            signed char* __restrict__ wq) {
    const int tid = threadIdx.x;
    if (blockIdx.x < 4096) {
        __shared__ float red[4];
        __shared__ float inv_s;
        const int m = blockIdx.x;
        const float4* xr = reinterpret_cast<const float4*>(x + (long)m * K_DIM);
        float4 v[4];
        float amax = 0.f;
#pragma unroll
        for (int j = 0; j < 4; ++j) {
            v[j] = xr[tid * 4 + j];
            amax = fmaxf(amax, fmaxf(fmaxf(fabsf(v[j].x), fabsf(v[j].y)),
                                     fmaxf(fabsf(v[j].z), fabsf(v[j].w))));
        }
#pragma unroll
        for (int off = 32; off >= 1; off >>= 1)
            amax = fmaxf(amax, __shfl_xor(amax, off));
        if ((tid & 63) == 0) red[tid >> 6] = amax;
        __syncthreads();
        if (tid == 0) {
            float a = fmaxf(fmaxf(red[0], red[1]), fmaxf(red[2], red[3]));
            sx[m] = a * (1.f / 127.f);
            inv_s = (a > 0.f) ? 127.f / a : 0.f;
        }
        __syncthreads();
        const float inv = inv_s;
        unsigned p[4];
#pragma unroll
        for (int j = 0; j < 4; ++j) {
            int a0 = __float2int_rn(v[j].x * inv);
            int a1 = __float2int_rn(v[j].y * inv);
            int a2 = __float2int_rn(v[j].z * inv);
            int a3 = __float2int_rn(v[j].w * inv);
            p[j] = (a0 & 255) | ((a1 & 255) << 8) | ((a2 & 255) << 16) | ((a3 & 255) << 24);
        }
        *reinterpret_cast<uint4*>(xq + (long)m * K_DIM + tid * 16) =
            make_uint4(p[0], p[1], p[2], p[3]);
        return;
    }
    // ---- wq half: tile = 128 k-rows x 32 n-cols, LDS transpose ----
    __shared__ signed char lt[128 * 32];
    const int bx = blockIdx.x - 4096;
    const int n0 = (bx & 127) * 32;
    const int k0 = (bx >> 7) * 128;     // tile spans exactly one scale group
    const int g  = bx >> 7;
    const int kl = tid >> 1;            // 0..127
    const int h  = tid & 1;
    int4 qv[4], zv[4];
#pragma unroll
    for (int c = 0; c < 4; ++c) {
        qv[c] = *reinterpret_cast<const int4*>(&qw[(long)(k0 + kl) * N_DIM + n0 + h * 16 + c * 4]);
        zv[c] = *reinterpret_cast<const int4*>(&zps[(long)g * N_DIM + n0 + h * 16 + c * 4]);
    }
    {
        const int swz = ((kl >> 3) & 7) << 2;
        int* ltw = reinterpret_cast<int*>(lt);
#pragma unroll
        for (int c = 0; c < 4; ++c) {
            unsigned d = (unsigned)((qv[c].x - zv[c].x) & 255)
                       | ((unsigned)((qv[c].y - zv[c].y) & 255) << 8)
                       | ((unsigned)((qv[c].z - zv[c].z) & 255) << 16)
                       | ((unsigned)((qv[c].w - zv[c].w) & 255) << 24);
            ltw[(kl * 32 + ((h * 16 + c * 4) ^ swz)) >> 2] = d;
        }
    }
    __syncthreads();
    const int nl = tid >> 3;            // 0..31
    const int kq = tid & 7;             // 0..7
    unsigned acc[4] = {0u, 0u, 0u, 0u};
#pragma unroll
    for (int j = 0; j < 16; ++j) {
        const int kr = kq * 16 + j;
        unsigned by = (unsigned char)lt[kr * 32 + (nl ^ (((kr >> 3) & 7) << 2))];
        acc[j >> 2] |= by << (8 * (j & 3));
    }
    *reinterpret_cast<uint4*>(wq + (long)(n0 + nl) * K_DIM + k0 + kq * 16) =
        make_uint4(acc[0], acc[1], acc[2], acc[3]);
}

// ---------------- main GEMM (i8): C = sx[m] * sum_g s[g][n]*(xq . wq) + bias
// Round-7 design: HIGH OCCUPANCY instead of intra-block asm scheduling (r5/r6
// both spilled via "memory"-clobber/sched_barrier codegen fights — banned).
// BM=128 BN=256 BK=64, 512 thr (8 waves 2x4), wave tile 64x64 (facc = 64
// regs). LDS = 2 x 24 KB = 48 KB dbuf; target <=128 VGPR via
// __launch_bounds__(512,4) -> 2 independent blocks/CU, 16 waves/CU (2x the
// r3 occupancy). Pipe overlap now comes from BLOCK independence (m114
// mechanism: separate waves overlap MFMA/VALU/LDS pipes fully) instead of
// the barrier-locked single block that serialized LDS->MFMA->VALU bursts in
// r0/r3. Balanced 64x64 wave tiles also cut LDS read traffic 33%.
// Structure is r3's verified serial loop: prefetch(t+1) -> compute(t) ->
// __syncthreads (drains vmcnt; prefetch had the whole compute phase). Zero
// inline asm. BK=64: group = 2 steps; rescale per step with the group's
// scales (same total VALU as r3: half elems x double freq; exact i8 within
// group). LDS 64B-row XOR swizzle phys = u ^ ((row>>1)&3): DMA writes are
// tid-linear (wave-uniform base + lane*16), reads verified uniform
// 8 dwords/bank -> data-floor, no serialization. A/B frags use the IDENTICAL
// (ks,half)->16B-unit k-bijection (r0/r3-verified principle), so correctness
// is independent of MFMA's internal k-order.
#define BM 128
#define BN 256
#define BK 64
#define NSTEP (K_DIM / BK)   // 64

__device__ __forceinline__ void async_ld16(const signed char* g, const signed char* l) {
    __builtin_amdgcn_global_load_lds(
        (const __attribute__((address_space(1))) void*)g,
        (__attribute__((address_space(3))) void*)l, 16, 0, 0);
}

__device__ __forceinline__ int16v mf(const int4v a, const int4v b, const int16v c) {
    return __builtin_amdgcn_mfma_i32_32x32x32_i8(a, b, c, 0, 0, 0);
}

__device__ __forceinline__ int4v ld_frag(const signed char* buf, int row, int lu) {
    const int phys = lu ^ ((row >> 1) & 3);
    return *reinterpret_cast<const int4v*>(&buf[row * BK + phys * 16]);
}

__global__ __launch_bounds__(512, 4) void gemm_kernel(
    const signed char* __restrict__ A,   // xq [M][K]
    const signed char* __restrict__ Bq,  // wq [N][K]
    const float* __restrict__ scales,    // [NG][N]
    const float* __restrict__ sx,        // [M]
    const float* __restrict__ bias,     // [N]
    float* __restrict__ C) {
    __shared__ signed char As[2][BM * BK];  // 2 x 8 KB
    __shared__ signed char Bs[2][BN * BK];  // 2 x 16 KB  (total 48 KB)
    const int tid  = threadIdx.x;
    const int wave = tid >> 6;
    const int lane = tid & 63;
    const int half = lane >> 5;
    const int l32  = lane & 31;
    const int wm = (wave >> 2) * 64;    // 2 wave-rows x 64
    const int wn = (wave & 3) * 64;     // 4 wave-cols x 64

    // bijective XCD swizzle: 512 blocks, 64 consecutive per XCD
    const int bid = (int)blockIdx.x;
    const int swz = (bid & 7) * 64 + (bid >> 3);
    const int m0 = (swz >> 4) * BM;     // 32 m-tiles
    const int n0 = (swz & 15) * BN;     // 16 n-tiles

    // DMA staging: thread -> (row = tid/4, 16B phys slot tid&3); global unit
    // = (tid&3) ^ ((row>>1)&3)  [involution matches ld_frag]. LDS offset
    // row*64 + (tid&3)*16 = tid*16 -> linear; dest base wave-uniform.
    const int srow  = tid >> 2;         // 0..127
    const int sunit = (tid & 3) ^ ((tid >> 3) & 3);
    const signed char* agp = A  + (long)(m0 + srow) * K_DIM + sunit * 16;
    const signed char* bgp = Bq + (long)(n0 + srow) * K_DIM + sunit * 16;
    const float* sp = scales + n0 + wn + l32;

    float facc[2][2][16];
#pragma unroll
    for (int mt = 0; mt < 2; ++mt)
#pragma unroll
        for (int nt = 0; nt < 2; ++nt)
#pragma unroll
            for (int r = 0; r < 16; ++r) facc[mt][nt][r] = 0.f;
    int16v zero16;
#pragma unroll
    for (int r = 0; r < 16; ++r) zero16[r] = 0;

    // prologue: stage step 0 into buffer 0 (A: 1 pass, B: 2 passes)
    async_ld16(agp,                      As[0] + wave * 1024);
    async_ld16(bgp,                      Bs[0] + wave * 1024);
    async_ld16(bgp + (long)128 * K_DIM,  Bs[0] + 8192 + wave * 1024);
    __syncthreads();

    float s0c = 0.f, s1c = 0.f;
    for (int t = 0; t < NSTEP; ++t) {
        const signed char* Ab = As[t & 1];
        const signed char* Bb = Bs[t & 1];
        // prefetch next step into the other buffer (drained at iter-end sync)
        if (t + 1 < NSTEP) {
            const long kn = (long)(t + 1) * BK;
            async_ld16(agp + kn,                     As[(t + 1) & 1] + wave * 1024);
            async_ld16(bgp + kn,                     Bs[(t + 1) & 1] + wave * 1024);
            async_ld16(bgp + (long)128 * K_DIM + kn, Bs[(t + 1) & 1] + 8192 + wave * 1024);
        }
        if ((t & 1) == 0) {   // new 128-k scale group every 2 steps
            s0c = sp[(long)(t >> 1) * N_DIM];
            s1c = sp[(long)(t >> 1) * N_DIM + 32];
        }
        int4v bf[2][2];
#pragma unroll
        for (int nt = 0; nt < 2; ++nt) {
            const int n = wn + nt * 32 + l32;
#pragma unroll
            for (int ks = 0; ks < 2; ++ks)
                bf[nt][ks] = ld_frag(Bb, n, 2 * ks + half);
        }
#pragma unroll
        for (int mt = 0; mt < 2; ++mt) {
            const int m = wm + mt * 32 + l32;
            int4v af[2];
#pragma unroll
            for (int ks = 0; ks < 2; ++ks)
                af[ks] = ld_frag(Ab, m, 2 * ks + half);
#pragma unroll
            for (int nt = 0; nt < 2; ++nt) {
                int16v c = mf(af[0], bf[nt][0], zero16);
                c = mf(af[1], bf[nt][1], c);
                const float s = nt ? s1c : s0c;
#pragma unroll
                for (int r = 0; r < 16; ++r)
                    facc[mt][nt][r] += s * (float)c[r];
            }
        }
        __syncthreads();
    }

    // epilogue: 32x32 C/D layout col=lane&31, row=(reg&3)+8*(reg>>2)+4*half
    float bv[2];
    bv[0] = bias[n0 + wn + l32];
    bv[1] = bias[n0 + wn + 32 + l32];
    const int rowh = half * 4;
#pragma unroll
    for (int mt = 0; mt < 2; ++mt) {
#pragma unroll
        for (int r = 0; r < 16; ++r) {
            const int row = (r & 3) + 8 * (r >> 2) + rowh;
            const int gm  = m0 + wm + mt * 32 + row;
            const float sxm = sx[gm];
            float* crow = C + (long)gm * N_DIM + n0 + wn;
            crow[l32]      = facc[mt][0][r] * sxm + bv[0];
            crow[32 + l32] = facc[mt][1][r] * sxm + bv[1];
        }
    }
}

extern "C" void kernel_launch(void* const* d_in, const int* in_sizes, int n_in,
                              void* d_out, int out_size, void* d_ws, size_t ws_size,
                              hipStream_t stream) {
    const float* x      = (const float*)d_in[0];
    const int*   qw     = (const int*)d_in[1];
    const float* scales = (const float*)d_in[2];
    const int*   zps    = (const int*)d_in[3];
    // d_in[4] = g_idx: standard non-permuted (k/128) — folded in.
    const float* bias   = (const float*)d_in[5];
    float* out = (float*)d_out;

    signed char* xq = (signed char*)d_ws;                                   // 16 MB
    signed char* wq = (signed char*)d_ws + (size_t)M_DIM * K_DIM;           // 16 MB
    float*       sx = (float*)((signed char*)d_ws + 2 * (size_t)M_DIM * K_DIM);  // 16 KB

    prep_kernel<<<8192, 256, 0, stream>>>(x, xq, sx, qw, zps, wq);
    gemm_kernel<<<(M_DIM / BM) * (N_DIM / BN), 512, 0, stream>>>(
        xq, wq, scales, sx, bias, out);
}

// Round 9
// 268.892 us; speedup vs baseline: 2.9257x; 1.0979x over previous
//
#include <hip/hip_runtime.h>
#include <hip/hip_bf16.h>

typedef int  int4v  __attribute__((ext_vector_type(4)));
typedef int  int16v __attribute__((ext_vector_type(16)));

#define M_DIM 4096
#define N_DIM 4096
#define K_DIM 4096
#define NG 32        // groups
#define GS 128       // group size

// ---------------- fused prepass ----------------
// blocks [0, 4096): per-row absmax-quantize x -> xq i8 [M][K], sx[m]=absmax/127
// blocks [4096, 8192): wq[n][k] = q[k][n] - zp[g][n]  (exact in i8, transposed
//   via LDS tile so global writes are 128B-contiguous)
__global__ void prep_kernel(const float* __restrict__ x,
                            signed char* __restrict__ xq,
                            float* __restrict__ sx,
                            const int* __restrict__ qw,
                            const int* __restrict__ zps,
                            signed char* __restrict__ wq) {
    const int tid = threadIdx.x;
    if (blockIdx.x < 4096) {
        __shared__ float red[4];
        __shared__ float inv_s;
        const int m = blockIdx.x;
        const float4* xr = reinterpret_cast<const float4*>(x + (long)m * K_DIM);
        float4 v[4];
        float amax = 0.f;
#pragma unroll
        for (int j = 0; j < 4; ++j) {
            v[j] = xr[tid * 4 + j];
            amax = fmaxf(amax, fmaxf(fmaxf(fabsf(v[j].x), fabsf(v[j].y)),
                                     fmaxf(fabsf(v[j].z), fabsf(v[j].w))));
        }
#pragma unroll
        for (int off = 32; off >= 1; off >>= 1)
            amax = fmaxf(amax, __shfl_xor(amax, off));
        if ((tid & 63) == 0) red[tid >> 6] = amax;
        __syncthreads();
        if (tid == 0) {
            float a = fmaxf(fmaxf(red[0], red[1]), fmaxf(red[2], red[3]));
            sx[m] = a * (1.f / 127.f);
            inv_s = (a > 0.f) ? 127.f / a : 0.f;
        }
        __syncthreads();
        const float inv = inv_s;
        unsigned p[4];
#pragma unroll
        for (int j = 0; j < 4; ++j) {
            int a0 = __float2int_rn(v[j].x * inv);
            int a1 = __float2int_rn(v[j].y * inv);
            int a2 = __float2int_rn(v[j].z * inv);
            int a3 = __float2int_rn(v[j].w * inv);
            p[j] = (a0 & 255) | ((a1 & 255) << 8) | ((a2 & 255) << 16) | ((a3 & 255) << 24);
        }
        *reinterpret_cast<uint4*>(xq + (long)m * K_DIM + tid * 16) =
            make_uint4(p[0], p[1], p[2], p[3]);
        return;
    }
    // ---- wq half: tile = 128 k-rows x 32 n-cols, LDS transpose ----
    __shared__ signed char lt[128 * 32];
    const int bx = blockIdx.x - 4096;
    const int n0 = (bx & 127) * 32;
    const int k0 = (bx >> 7) * 128;     // tile spans exactly one scale group
    const int g  = bx >> 7;
    const int kl = tid >> 1;            // 0..127
    const int h  = tid & 1;
    int4 qv[4], zv[4];
#pragma unroll
    for (int c = 0; c < 4; ++c) {
        qv[c] = *reinterpret_cast<const int4*>(&qw[(long)(k0 + kl) * N_DIM + n0 + h * 16 + c * 4]);
        zv[c] = *reinterpret_cast<const int4*>(&zps[(long)g * N_DIM + n0 + h * 16 + c * 4]);
    }
    {
        const int swz = ((kl >> 3) & 7) << 2;
        int* ltw = reinterpret_cast<int*>(lt);
#pragma unroll
        for (int c = 0; c < 4; ++c) {
            unsigned d = (unsigned)((qv[c].x - zv[c].x) & 255)
                       | ((unsigned)((qv[c].y - zv[c].y) & 255) << 8)
                       | ((unsigned)((qv[c].z - zv[c].z) & 255) << 16)
                       | ((unsigned)((qv[c].w - zv[c].w) & 255) << 24);
            ltw[(kl * 32 + ((h * 16 + c * 4) ^ swz)) >> 2] = d;
        }
    }
    __syncthreads();
    const int nl = tid >> 3;            // 0..31
    const int kq = tid & 7;             // 0..7
    unsigned acc[4] = {0u, 0u, 0u, 0u};
#pragma unroll
    for (int j = 0; j < 16; ++j) {
        const int kr = kq * 16 + j;
        unsigned by = (unsigned char)lt[kr * 32 + (nl ^ (((kr >> 3) & 7) << 2))];
        acc[j >> 2] |= by << (8 * (j & 3));
    }
    *reinterpret_cast<uint4*>(wq + (long)(n0 + nl) * K_DIM + k0 + kq * 16) =
        make_uint4(acc[0], acc[1], acc[2], acc[3]);
}

// ---------------- main GEMM (i8): C = sx[m] * sum_g s[g][n]*(xq . wq) + bias
// Round-9 = round-8 resubmitted byte-equivalent (audit found no defect; the
// identical error string occurred on rounds 1-2 for source that then PASSED
// unchanged on round 3 -> discriminating infra-flake vs source).
// Design: r0's verified fat iteration (BK=128, wave tile 128x64, 0.75
// LDS-reads/MFMA, 32 iters) repackaged into 128x128 blocks of TWO waves ->
// 4 independent blocks/CU (LDS 32 KB, grid 1024). r7 post-mortem: small
// wave tiles (64x64) + BK=64 bloated VALU (59 us busy) and LDS reads (ratio
// 1.0) -- both reverted here; per-thread code is IDENTICAL to r0 (wm=0).
// Overlap mechanism is m114 cross-block co-scheduling: waves of different
// blocks on one SIMD interleave MFMA bursts with other blocks' LDS/VALU
// bursts, instead of the barrier-locked single-block serialization that
// pinned r0/r3 at ~100 us (MFMA pipe already at its ~29 us floor there).
// Zero inline asm (r5/r6 lesson: fences+clobbers around live 128-reg acc
// cause catastrophic spills). Serial stage->sync->compute->sync skeleton
// (r0-verified; __syncthreads' vmcnt(0) drain is the DMA wait). Scales read
// per-iter from L2 (512 KB table); sx/bias in epilogue from L2. XOR swizzle
// on 16B slots within 128B LDS rows; A/B frags use the IDENTICAL
// (ks,half)->16B-unit k-bijection (correctness independent of MFMA k-order).
#define BM 128
#define BN 128
#define BK 128
#define NT (K_DIM / BK)   // 32

__device__ __forceinline__ void async_ld16(const signed char* g, const signed char* l) {
    __builtin_amdgcn_global_load_lds(
        (const __attribute__((address_space(1))) void*)g,
        (__attribute__((address_space(3))) void*)l, 16, 0, 0);
}

__device__ __forceinline__ int16v mf(const int4v a, const int4v b, const int16v c) {
    return __builtin_amdgcn_mfma_i32_32x32x32_i8(a, b, c, 0, 0, 0);
}

__global__ __launch_bounds__(128, 2) void gemm_kernel(
    const signed char* __restrict__ A,   // xq [M][K]
    const signed char* __restrict__ Bq,  // wq [N][K]
    const float* __restrict__ scales,    // [NG][N]
    const float* __restrict__ sx,        // [M]
    const float* __restrict__ bias,      // [N]
    float* __restrict__ C) {
    __shared__ signed char As[BM * BK];  // 16 KB
    __shared__ signed char Bs[BN * BK];  // 16 KB   (total 32 KB -> 4-5 blocks/CU)
    const int tid  = threadIdx.x;        // 0..127 (2 waves)
    const int wave = tid >> 6;
    const int lane = tid & 63;
    const int half = lane >> 5;
    const int l32  = lane & 31;
    const int wn = wave * 64;            // wave tile: all 128 m-rows x 64 n-cols

    // bijective XCD swizzle: 1024 blocks, 128 consecutive per XCD
    const int bid = (int)blockIdx.x;
    const int swz = (bid & 7) * 128 + (bid >> 3);
    const int m0 = (swz >> 5) * BM;      // 32 m-tiles
    const int n0 = (swz & 31) * BN;      // 32 n-tiles

    // DMA staging: pass p covers rows p*16 + tid/8; 16B slot = (tid&7)^(row&7)
    // involution; LDS dest linear (tid*16 within each 2 KB pass-chunk).
    const int srow  = tid >> 3;          // 0..15
    const int sunit = (tid & 7) ^ (srow & 7);
    const signed char* agp = A  + (long)(m0 + srow) * K_DIM + sunit * 16;
    const signed char* bgp = Bq + (long)(n0 + srow) * K_DIM + sunit * 16;
    const float* sp = scales + n0 + wn + l32;   // per-lane scale column

    float facc[4][2][16];
#pragma unroll
    for (int mt = 0; mt < 4; ++mt)
#pragma unroll
        for (int nt = 0; nt < 2; ++nt)
#pragma unroll
            for (int r = 0; r < 16; ++r) facc[mt][nt][r] = 0.f;
    int16v zero16;
#pragma unroll
    for (int r = 0; r < 16; ++r) zero16[r] = 0;

    for (int t = 0; t < NT; ++t) {
        const long kk = (long)t * BK;
#pragma unroll
        for (int p = 0; p < 8; ++p) {    // 16 rows per pass, 8 passes each
            async_ld16(agp + (long)(p * 16) * K_DIM + kk, As + p * 2048 + wave * 1024);
            async_ld16(bgp + (long)(p * 16) * K_DIM + kk, Bs + p * 2048 + wave * 1024);
        }
        __syncthreads();                 // drains DMA (vmcnt 0) + barrier

        const float s0 = sp[(long)t * N_DIM];        // group g = t (BK == GS)
        const float s1 = sp[(long)t * N_DIM + 32];
        int4v bf[2][4];
#pragma unroll
        for (int nt = 0; nt < 2; ++nt) {
            const int n = wn + nt * 32 + l32;
#pragma unroll
            for (int ks = 0; ks < 4; ++ks) {
                const int slot = (2 * ks + half) ^ (n & 7);
                bf[nt][ks] = *reinterpret_cast<const int4v*>(&Bs[n * BK + slot * 16]);
            }
        }
#pragma unroll
        for (int mt = 0; mt < 4; ++mt) {
            const int m = mt * 32 + l32;
            int4v af[4];
#pragma unroll
            for (int ks = 0; ks < 4; ++ks) {
                const int slot = (2 * ks + half) ^ (m & 7);
                af[ks] = *reinterpret_cast<const int4v*>(&As[m * BK + slot * 16]);
            }
            int16v c0 = mf(af[0], bf[0][0], zero16);
            int16v c1 = mf(af[0], bf[1][0], zero16);
#pragma unroll
            for (int ks = 1; ks < 4; ++ks) {
                c0 = mf(af[ks], bf[0][ks], c0);
                c1 = mf(af[ks], bf[1][ks], c1);
            }
#pragma unroll
            for (int r = 0; r < 16; ++r) {
                facc[mt][0][r] += s0 * (float)c0[r];
                facc[mt][1][r] += s1 * (float)c1[r];
            }
        }
        __syncthreads();                 // all reads done before next overwrite
    }

    // epilogue: 32x32 C/D layout col=lane&31, row=(reg&3)+8*(reg>>2)+4*half
    float bv[2];
    bv[0] = bias[n0 + wn + l32];
    bv[1] = bias[n0 + wn + 32 + l32];
    const int rowh = half * 4;
#pragma unroll
    for (int mt = 0; mt < 4; ++mt) {
#pragma unroll
        for (int r = 0; r < 16; ++r) {
            const int row = (r & 3) + 8 * (r >> 2) + rowh;
            const int gm  = m0 + mt * 32 + row;
            const float sxm = sx[gm];
            float* crow = C + (long)gm * N_DIM + n0 + wn;
            crow[l32]      = facc[mt][0][r] * sxm + bv[0];
            crow[32 + l32] = facc[mt][1][r] * sxm + bv[1];
        }
    }
}

extern "C" void kernel_launch(void* const* d_in, const int* in_sizes, int n_in,
                              void* d_out, int out_size, void* d_ws, size_t ws_size,
                              hipStream_t stream) {
    const float* x      = (const float*)d_in[0];
    const int*   qw     = (const int*)d_in[1];
    const float* scales = (const float*)d_in[2];
    const int*   zps    = (const int*)d_in[3];
    // d_in[4] = g_idx: standard non-permuted (k/128) — folded in.
    const float* bias   = (const float*)d_in[5];
    float* out = (float*)d_out;

    signed char* xq = (signed char*)d_ws;                                   // 16 MB
    signed char* wq = (signed char*)d_ws + (size_t)M_DIM * K_DIM;           // 16 MB
    float*       sx = (float*)((signed char*)d_ws + 2 * (size_t)M_DIM * K_DIM);  // 16 KB

    prep_kernel<<<8192, 256, 0, stream>>>(x, xq, sx, qw, zps, wq);
    gemm_kernel<<<(M_DIM / BM) * (N_DIM / BN), 128, 0, stream>>>(
        xq, wq, scales, sx, bias, out);
}